// Round 2
// baseline (58.424 us; speedup 1.0000x reference)
//
#include <hip/hip_runtime.h>
#include <cstddef>

// Problem constants
#define BB   128
#define NN   256
#define DIMD 256
#define MSG  64
#define CDIM 32
#define TOPK 8
#define H1D  128
#define H2D  256
#define BN   (BB*NN)   // 32768 rows

typedef unsigned short u16;
typedef u16   u16x4  __attribute__((ext_vector_type(4)));
typedef u16   u16x8  __attribute__((ext_vector_type(8)));
typedef short short8 __attribute__((ext_vector_type(8)));
typedef float f32x4  __attribute__((ext_vector_type(4)));

__device__ __forceinline__ u16 f2bf(float f) {
    return (u16)((__float_as_uint(f) + 0x8000u) >> 16);
}
__device__ __forceinline__ float bf2f(u16 u) {
    return __uint_as_float(((unsigned)u) << 16);
}
#define MFMA16(a,b,c) __builtin_amdgcn_mfma_f32_16x16x32_bf16((a),(b),(c),0,0,0)

// Fragment-linear packing (global): elem (tile=row/16, ls=row%16, kk=k/32,
// q=(k%32)/8, j=k%8) at ((tile*KB+kk)*64 + q*16 + ls)*8 + j. A wave's
// fragment load is one coalesced 1KB transaction.

// ---------------------------------------------------------------------------
// prep: weights fp32 [in][out] -> packed bf16. 1008 blocks exactly.
// ---------------------------------------------------------------------------
__global__ __launch_bounds__(256) void prep_w_k(
    const float* __restrict__ W1, const float* __restrict__ W2,
    const float* __restrict__ Wc, const float* __restrict__ Wd,
    const float* __restrict__ Wb, const float* __restrict__ Wr1,
    const float* __restrict__ Wr2,
    u16* __restrict__ Wp1, u16* __restrict__ Wp2, u16* __restrict__ Wpc,
    u16* __restrict__ Wpd, u16* __restrict__ WpB, u16* __restrict__ Wpr1,
    u16* __restrict__ Wpr2)
{
    const int t = blockIdx.x * 256 + threadIdx.x;   // 258048 exactly
    const float* src; u16* dst; int I, os, loc;
    if      (t <  32768) { src = W1;  dst = Wp1;  I = 256; os = 7; loc = t; }
    else if (t <  40960) { src = W2;  dst = Wp2;  I = 128; os = 6; loc = t - 32768; }
    else if (t <  43008) { src = Wc;  dst = Wpc;  I = 64;  os = 5; loc = t - 40960; }
    else if (t <  45056) { src = Wd;  dst = Wpd;  I = 32;  os = 6; loc = t - 43008; }
    else if (t < 110592) { src = Wb;  dst = WpB;  I = 256; os = 8; loc = t - 45056; }
    else if (t < 192512) { src = Wr1; dst = Wpr1; I = 320; os = 8; loc = t - 110592; }
    else                 { src = Wr2; dst = Wpr2; I = 256; os = 8; loc = t - 192512; }
    const int i = loc >> os;
    const int o = loc & ((1 << os) - 1);
    const int nt = o >> 4, ls = o & 15;
    const int KB = I >> 5;
    const int kk = i >> 5, q = (i & 31) >> 3, j = i & 7;
    dst[((size_t)(nt*KB + kk)*64 + q*16 + ls)*8 + j] = f2bf(src[loc]);
}

// ---------------------------------------------------------------------------
// sendpack: 32 rows/block, 4 waves. Stages fp32 obs -> bf16 LDS, emits
// packed obs_p (coalesced), runs the 4-layer send MLP (L1 A from LDS,
// B prefetched), writes msgs. Replaces the old obs-prep pass entirely.
// ---------------------------------------------------------------------------
__global__ __launch_bounds__(256) __attribute__((amdgpu_waves_per_eu(4, 4)))
void sendpack_k(
    const float* __restrict__ obs, u16* __restrict__ obs_p,
    const u16* __restrict__ Wp1, const float* __restrict__ b1,
    const u16* __restrict__ Wp2, const float* __restrict__ b2,
    const u16* __restrict__ Wpc, const float* __restrict__ bc,
    const u16* __restrict__ Wpd, const float* __restrict__ bd,
    u16* __restrict__ msgs_bf)
{
    __shared__ __align__(16) u16 sO[32][264];
    __shared__ __align__(16) u16 sH[32][136];
    __shared__ __align__(16) u16 sF[32][72];
    __shared__ __align__(16) u16 sC[32][40];
    const int t = threadIdx.x;
    const int w = t >> 6, l = t & 63, q = l >> 4, ls = l & 15;
    const int row0 = blockIdx.x * 32;
    const int tile0 = blockIdx.x * 2;

    // stage obs fp32 -> bf16 LDS (coalesced reads, one row per wave-step)
    {
        const float4* src = (const float4*)(obs + (size_t)row0 * 256);
        #pragma unroll
        for (int i = 0; i < 8; ++i) {
            const int idx = t + 256*i;
            const int r = idx >> 6, c4 = idx & 63;
            const float4 v = src[idx];
            u16x4 o;
            o[0] = f2bf(v.x); o[1] = f2bf(v.y); o[2] = f2bf(v.z); o[3] = f2bf(v.w);
            *(u16x4*)&sO[r][c4*4] = o;
        }
    }
    __syncthreads();
    // emit packed obs_p: LDS b128 reads -> coalesced 1KB global stores
    {
        #pragma unroll
        for (int i = 0; i < 4; ++i) {
            const int u = t + 256*i;                 // 1024 u16x8 units
            const int tile = u >> 9, kk = (u >> 6) & 7, lane = u & 63;
            const u16x8 v = *(const u16x8*)&sO[tile*16 + (lane & 15)][kk*32 + (lane >> 4)*8];
            *(u16x8*)(obs_p + (size_t)(tile0 + tile)*4096 + (size_t)(kk*64 + lane)*8) = v;
        }
    }
    // L1: 256 -> 128, relu; wave owns n-tiles {2w,2w+1}; A from LDS, B prefetched
    {
        f32x4 acc[2][2];
        #pragma unroll
        for (int mi = 0; mi < 2; ++mi)
            #pragma unroll
            for (int nn = 0; nn < 2; ++nn) acc[mi][nn] = (f32x4){0,0,0,0};
        short8 cb[2];
        #pragma unroll
        for (int nn = 0; nn < 2; ++nn)
            cb[nn] = *(const short8*)(Wp1 + ((size_t)((w*2+nn)*8))*512 + l*8);
        #pragma unroll
        for (int kk = 0; kk < 8; ++kk) {
            short8 nb[2];
            if (kk < 7) {
                #pragma unroll
                for (int nn = 0; nn < 2; ++nn)
                    nb[nn] = *(const short8*)(Wp1 + ((size_t)((w*2+nn)*8 + kk+1))*512 + l*8);
            }
            short8 a[2];
            a[0] = *(const short8*)&sO[ls][kk*32 + q*8];
            a[1] = *(const short8*)&sO[16 + ls][kk*32 + q*8];
            #pragma unroll
            for (int mi = 0; mi < 2; ++mi)
                #pragma unroll
                for (int nn = 0; nn < 2; ++nn)
                    acc[mi][nn] = MFMA16(a[mi], cb[nn], acc[mi][nn]);
            if (kk < 7) {
                #pragma unroll
                for (int nn = 0; nn < 2; ++nn) cb[nn] = nb[nn];
            }
        }
        #pragma unroll
        for (int nn = 0; nn < 2; ++nn) {
            const float bv = b1[(w*2+nn)*16 + ls];
            #pragma unroll
            for (int mi = 0; mi < 2; ++mi)
                #pragma unroll
                for (int r = 0; r < 4; ++r)
                    sH[mi*16 + q*4 + r][(w*2+nn)*16 + ls] = f2bf(fmaxf(acc[mi][nn][r] + bv, 0.0f));
        }
    }
    __syncthreads();
    // L2: 128 -> 64; wave owns n-tile w
    {
        f32x4 acc[2];
        acc[0] = (f32x4){0,0,0,0}; acc[1] = (f32x4){0,0,0,0};
        #pragma unroll
        for (int kk = 0; kk < 4; ++kk) {
            const int k0 = kk * 32;
            short8 a[2];
            a[0] = *(const short8*)(&sH[ls][k0 + q*8]);
            a[1] = *(const short8*)(&sH[16 + ls][k0 + q*8]);
            const short8 bf = *(const short8*)(Wp2 + ((size_t)(w*4 + kk)*64 + l)*8);
            acc[0] = MFMA16(a[0], bf, acc[0]);
            acc[1] = MFMA16(a[1], bf, acc[1]);
        }
        const float bv = b2[w*16 + ls];
        #pragma unroll
        for (int mi = 0; mi < 2; ++mi)
            #pragma unroll
            for (int r = 0; r < 4; ++r)
                sF[mi*16 + q*4 + r][w*16 + ls] = f2bf(acc[mi][r] + bv);
    }
    __syncthreads();
    // L3: 64 -> 32; waves 0,1 active
    if (w < 2) {
        f32x4 acc[2];
        acc[0] = (f32x4){0,0,0,0}; acc[1] = (f32x4){0,0,0,0};
        #pragma unroll
        for (int kk = 0; kk < 2; ++kk) {
            const int k0 = kk * 32;
            short8 a[2];
            a[0] = *(const short8*)(&sF[ls][k0 + q*8]);
            a[1] = *(const short8*)(&sF[16 + ls][k0 + q*8]);
            const short8 bf = *(const short8*)(Wpc + ((size_t)(w*2 + kk)*64 + l)*8);
            acc[0] = MFMA16(a[0], bf, acc[0]);
            acc[1] = MFMA16(a[1], bf, acc[1]);
        }
        const float bv = bc[w*16 + ls];
        #pragma unroll
        for (int mi = 0; mi < 2; ++mi)
            #pragma unroll
            for (int r = 0; r < 4; ++r)
                sC[mi*16 + q*4 + r][w*16 + ls] = f2bf(acc[mi][r] + bv);
    }
    __syncthreads();
    // L4: 32 -> 64; wave owns n-tile w; write msgs (row-major)
    {
        f32x4 acc[2];
        acc[0] = (f32x4){0,0,0,0}; acc[1] = (f32x4){0,0,0,0};
        short8 a[2];
        a[0] = *(const short8*)(&sC[ls][q*8]);
        a[1] = *(const short8*)(&sC[16 + ls][q*8]);
        const short8 bf = *(const short8*)(Wpd + ((size_t)w*64 + l)*8);
        acc[0] = MFMA16(a[0], bf, acc[0]);
        acc[1] = MFMA16(a[1], bf, acc[1]);
        const float bv = bd[w*16 + ls];
        #pragma unroll
        for (int mi = 0; mi < 2; ++mi)
            #pragma unroll
            for (int r = 0; r < 4; ++r)
                msgs_bf[(size_t)(row0 + mi*16 + q*4 + r)*MSG + w*16 + ls] = f2bf(acc[mi][r] + bv);
    }
}

// ---------------------------------------------------------------------------
// relrecv (fused): 64 rows of one batch per block, 512 threads / 8 waves.
//  Rationale: every block must read full weight panels (WpB, Wpr1, Wpr2) and
//  the batch's packed obs; doubling M per block halves that L2 traffic per
//  row (~600 -> ~340 MB chip-wide). Wave owns 4 m-tiles x 2 n-tiles (same
//  64 MFMA/phase, half the B loads). LDS ~77KB -> 2 blocks/CU = 16 waves/CU
//  (occupancy unchanged vs the 32-row version).
// ---------------------------------------------------------------------------
__global__ __launch_bounds__(512) __attribute__((amdgpu_waves_per_eu(4, 4)))
void relrecv_k(
    const u16* __restrict__ obs_p, const u16* __restrict__ WpB,
    const float* __restrict__ bbil, const u16* __restrict__ msgs_bf,
    const u16* __restrict__ Wpr1, const float* __restrict__ br1,
    const u16* __restrict__ Wpr2, const float* __restrict__ br2,
    float* __restrict__ out)
{
    __shared__ __align__(16) u16 sS[64][264];   // tmp -> scores -> recvL1 out
    __shared__ __align__(16) u16 sA[64][72];    // agg, row-major [row][k]
    __shared__ __align__(16) u16 sObs[16384];   // block's 4 packed obs tiles
    __shared__ float sG[64][8];
    __shared__ unsigned short sI[64][8];
    const int t = threadIdx.x;
    const int w = t >> 6, l = t & 63, q = l >> 4, ls = l & 15;
    const int bid = blockIdx.x;        // 512
    const int xcd = bid & 7, idx = bid >> 3;   // idx in [0,64)
    const int b   = xcd * 16 + (idx >> 2);     // batch
    const int mc  = idx & 3;                   // 64-row chunk
    const int row0g = b * NN + mc * 64;
    const int mt0   = b * 16 + mc * 4;         // first of 4 m-tiles

    short8 pb[3][2];   // B-fragment pipeline buffers (reused per phase)

    // stage block's own obs tiles -> LDS (32KB contiguous, coalesced)
    {
        const u16x8* src = (const u16x8*)(obs_p + (size_t)mt0 * 4096);
        #pragma unroll
        for (int i = 0; i < 4; ++i)
            *(u16x8*)&sObs[(t + 512*i) * 8] = src[t + 512*i];
    }
    // P2 B preload (depth 2) — issued before the barrier; drains during wait
    #pragma unroll
    for (int d = 0; d < 2; ++d)
        #pragma unroll
        for (int nn = 0; nn < 2; ++nn)
            pb[d][nn] = *(const short8*)(WpB + ((size_t)((w*2+nn)*8 + d))*512 + l*8);
    __syncthreads();

    // P2: tmp[m][e]; wave owns e-tiles {2w,2w+1}; A from sObs, B 3-buffered
    {
        f32x4 acc[4][2];
        #pragma unroll
        for (int mi = 0; mi < 4; ++mi)
            #pragma unroll
            for (int nn = 0; nn < 2; ++nn) acc[mi][nn] = (f32x4){0,0,0,0};
        #pragma unroll
        for (int kk = 0; kk < 8; ++kk) {
            if (kk < 6) {
                #pragma unroll
                for (int nn = 0; nn < 2; ++nn)
                    pb[(kk+2)%3][nn] = *(const short8*)(WpB + ((size_t)((w*2+nn)*8 + kk+2))*512 + l*8);
            }
            short8 a[4];
            #pragma unroll
            for (int mi = 0; mi < 4; ++mi)
                a[mi] = *(const short8*)&sObs[mi*4096 + kk*512 + l*8];
            #pragma unroll
            for (int mi = 0; mi < 4; ++mi)
                #pragma unroll
                for (int nn = 0; nn < 2; ++nn)
                    acc[mi][nn] = MFMA16(a[mi], pb[kk%3][nn], acc[mi][nn]);
        }
        #pragma unroll
        for (int mi = 0; mi < 4; ++mi)
            #pragma unroll
            for (int nn = 0; nn < 2; ++nn)
                #pragma unroll
                for (int r = 0; r < 4; ++r)
                    sS[mi*16 + q*4 + r][(w*2+nn)*16 + ls] = f2bf(acc[mi][nn][r]);
    }
    // P3 B preload (obs_p batch rows) before the barrier
    #pragma unroll
    for (int d = 0; d < 2; ++d)
        #pragma unroll
        for (int nn = 0; nn < 2; ++nn)
            pb[d][nn] = *(const short8*)(obs_p + ((size_t)((b*16 + w*2+nn)*8 + d))*512 + l*8);
    __syncthreads();

    // P3: scores[m][j]; A (tmp) from LDS, B = packed obs_b rows, 3-buffered
    {
        const float bb = bbil[0];
        f32x4 acc[4][2];
        #pragma unroll
        for (int mi = 0; mi < 4; ++mi)
            #pragma unroll
            for (int nn = 0; nn < 2; ++nn) acc[mi][nn] = (f32x4){0,0,0,0};
        #pragma unroll
        for (int kk = 0; kk < 8; ++kk) {
            if (kk < 6) {
                #pragma unroll
                for (int nn = 0; nn < 2; ++nn)
                    pb[(kk+2)%3][nn] = *(const short8*)(obs_p + ((size_t)((b*16 + w*2+nn)*8 + kk+2))*512 + l*8);
            }
            const int k0 = kk * 32;
            short8 a[4];
            #pragma unroll
            for (int mi = 0; mi < 4; ++mi)
                a[mi] = *(const short8*)(&sS[mi*16 + ls][k0 + q*8]);
            #pragma unroll
            for (int mi = 0; mi < 4; ++mi)
                #pragma unroll
                for (int nn = 0; nn < 2; ++nn)
                    acc[mi][nn] = MFMA16(a[mi], pb[kk%3][nn], acc[mi][nn]);
        }
        __syncthreads();   // all tmp reads complete before overwrite
        #pragma unroll
        for (int mi = 0; mi < 4; ++mi)
            #pragma unroll
            for (int nn = 0; nn < 2; ++nn)
                #pragma unroll
                for (int r = 0; r < 4; ++r)
                    sS[mi*16 + q*4 + r][(w*2+nn)*16 + ls] = f2bf(acc[mi][nn][r] + bb);
    }
    __syncthreads();
    // scan: 8 threads/row; 512 threads cover 64 rows exactly
    {
        const int r = t >> 3, g = t & 7;
        u16 buf[32];
        #pragma unroll
        for (int c = 0; c < 4; ++c)
            *(u16x8*)&buf[c*8] = *(const u16x8*)&sS[r][g*32 + c*8];
        float val[8]; int idx8[8];
        #pragma unroll
        for (int j = 0; j < 8; ++j) { val[j] = -3.4028235e38f; idx8[j] = 1 << 30; }
        #pragma unroll
        for (int i = 0; i < 32; ++i) {
            const int   id = g*32 + i;
            const float v  = bf2f(buf[i]);
            if (v > val[7]) {   // semantics-preserving early skip (strict >)
                #pragma unroll
                for (int j = 7; j >= 1; --j) {
                    const bool cj  = v > val[j];
                    const bool cjm = v > val[j-1];
                    val[j]  = cj ? (cjm ? val[j-1]  : v ) : val[j];
                    idx8[j] = cj ? (cjm ? idx8[j-1] : id) : idx8[j];
                }
                const bool c0 = v > val[0];
                val[0]  = c0 ? v  : val[0];
                idx8[0] = c0 ? id : idx8[0];
            }
        }
        float wv[8]; int wi[8];
        #pragma unroll
        for (int k = 0; k < 8; ++k) {
            float hv = val[0]; int hi = idx8[0];
            float ov; int oi;
            ov = __shfl_xor(hv, 1); oi = __shfl_xor(hi, 1);
            if (ov > hv || (ov == hv && oi < hi)) { hv = ov; hi = oi; }
            ov = __shfl_xor(hv, 2); oi = __shfl_xor(hi, 2);
            if (ov > hv || (ov == hv && oi < hi)) { hv = ov; hi = oi; }
            ov = __shfl_xor(hv, 4); oi = __shfl_xor(hi, 4);
            if (ov > hv || (ov == hv && oi < hi)) { hv = ov; hi = oi; }
            wv[k] = hv; wi[k] = hi;
            const bool won = (val[0] == hv) && (idx8[0] == hi);
            #pragma unroll
            for (int j = 0; j < 7; ++j) {
                val[j]  = won ? val[j+1]  : val[j];
                idx8[j] = won ? idx8[j+1] : idx8[j];
            }
            val[7]  = won ? -3.4028235e38f : val[7];
            idx8[7] = won ? (1 << 30)      : idx8[7];
        }
        if (g == 0) {
            float e[8]; float s = 0.0f;
            #pragma unroll
            for (int k = 0; k < 8; ++k) { e[k] = __expf(wv[k] - wv[0]); s += e[k]; }
            const float inv = 1.0f / s;
            #pragma unroll
            for (int k = 0; k < 8; ++k) {
                sG[r][k] = e[k] * inv;
                sI[r][k] = (unsigned short)wi[k];
            }
        }
    }
    // L1 B preload issued here — covered by the whole gather phase
    #pragma unroll
    for (int d = 0; d < 2; ++d)
        #pragma unroll
        for (int nn = 0; nn < 2; ++nn)
            pb[d][nn] = *(const short8*)(Wpr1 + ((size_t)((w*2+nn)*10 + d))*512 + l*8);
    // no barrier: sG/sI/gather rows are wave-private (wave w owns rows w*8..+7)
    // gather-aggregate: lane = msg column; fully unrolled so 64 loads pipeline
    {
        const u16* mb = msgs_bf + (size_t)b*NN*MSG + l;
        #pragma unroll
        for (int rr = 0; rr < 8; ++rr) {
            const int row = w*8 + rr;
            u16 mv[8];
            #pragma unroll
            for (int k = 0; k < 8; ++k)
                mv[k] = mb[(size_t)sI[row][k]*MSG];
            float a = 0.0f;
            #pragma unroll
            for (int k = 0; k < 8; ++k)
                a = fmaf(sG[row][k], bf2f(mv[k]), a);
            sA[row][l] = f2bf(a);
        }
    }
    __syncthreads();
    // recv L1: K=320 -> 256, relu; A: obs (sObs LDS, kk<8) + agg (sA, kk 8,9)
    {
        f32x4 acc[4][2];
        #pragma unroll
        for (int mi = 0; mi < 4; ++mi)
            #pragma unroll
            for (int nn = 0; nn < 2; ++nn) acc[mi][nn] = (f32x4){0,0,0,0};
        #pragma unroll
        for (int kk = 0; kk < 10; ++kk) {
            if (kk < 8) {
                #pragma unroll
                for (int nn = 0; nn < 2; ++nn)
                    pb[(kk+2)%3][nn] = *(const short8*)(Wpr1 + ((size_t)((w*2+nn)*10 + kk+2))*512 + l*8);
            }
            short8 a[4];
            if (kk < 8) {
                #pragma unroll
                for (int mi = 0; mi < 4; ++mi)
                    a[mi] = *(const short8*)&sObs[mi*4096 + kk*512 + l*8];
            } else {
                #pragma unroll
                for (int mi = 0; mi < 4; ++mi)
                    a[mi] = *(const short8*)&sA[mi*16 + ls][(kk-8)*32 + q*8];
            }
            #pragma unroll
            for (int mi = 0; mi < 4; ++mi)
                #pragma unroll
                for (int nn = 0; nn < 2; ++nn)
                    acc[mi][nn] = MFMA16(a[mi], pb[kk%3][nn], acc[mi][nn]);
        }
        // L2 B preload before the barrier (drains during epilogue + waits)
        #pragma unroll
        for (int d = 0; d < 2; ++d)
            #pragma unroll
            for (int nn = 0; nn < 2; ++nn)
                pb[d][nn] = *(const short8*)(Wpr2 + ((size_t)((w*2+nn)*8 + d))*512 + l*8);
        __syncthreads();   // sS scores fully consumed (scan done) before reuse
        #pragma unroll
        for (int nn = 0; nn < 2; ++nn) {
            const float bv = br1[(w*2+nn)*16 + ls];
            #pragma unroll
            for (int mi = 0; mi < 4; ++mi)
                #pragma unroll
                for (int r = 0; r < 4; ++r)
                    sS[mi*16 + q*4 + r][(w*2+nn)*16 + ls] = f2bf(fmaxf(acc[mi][nn][r] + bv, 0.0f));
        }
    }
    __syncthreads();
    // recv L2: 256 -> 256, fp32 out; A from LDS, B Wpr2 3-buffered
    {
        f32x4 acc[4][2];
        #pragma unroll
        for (int mi = 0; mi < 4; ++mi)
            #pragma unroll
            for (int nn = 0; nn < 2; ++nn) acc[mi][nn] = (f32x4){0,0,0,0};
        #pragma unroll
        for (int kk = 0; kk < 8; ++kk) {
            if (kk < 6) {
                #pragma unroll
                for (int nn = 0; nn < 2; ++nn)
                    pb[(kk+2)%3][nn] = *(const short8*)(Wpr2 + ((size_t)((w*2+nn)*8 + kk+2))*512 + l*8);
            }
            const int k0 = kk * 32;
            short8 a[4];
            #pragma unroll
            for (int mi = 0; mi < 4; ++mi)
                a[mi] = *(const short8*)(&sS[mi*16 + ls][k0 + q*8]);
            #pragma unroll
            for (int mi = 0; mi < 4; ++mi)
                #pragma unroll
                for (int nn = 0; nn < 2; ++nn)
                    acc[mi][nn] = MFMA16(a[mi], pb[kk%3][nn], acc[mi][nn]);
        }
        #pragma unroll
        for (int nn = 0; nn < 2; ++nn) {
            const float bv = br2[(w*2+nn)*16 + ls];
            #pragma unroll
            for (int mi = 0; mi < 4; ++mi)
                #pragma unroll
                for (int r = 0; r < 4; ++r)
                    out[(size_t)(row0g + mi*16 + q*4 + r)*DIMD + (w*2+nn)*16 + ls] = acc[mi][nn][r] + bv;
        }
    }
}

// ---------------------------------------------------------------------------
extern "C" void kernel_launch(void* const* d_in, const int* in_sizes, int n_in,
                              void* d_out, int out_size, void* d_ws, size_t ws_size,
                              hipStream_t stream)
{
    (void)in_sizes; (void)n_in; (void)out_size; (void)ws_size;
    const float* obs  = (const float*)d_in[0];
    const float* W1   = (const float*)d_in[1];
    const float* b1   = (const float*)d_in[2];
    const float* W2   = (const float*)d_in[3];
    const float* b2   = (const float*)d_in[4];
    const float* Wc   = (const float*)d_in[5];
    const float* bc   = (const float*)d_in[6];
    const float* Wd   = (const float*)d_in[7];
    const float* bd   = (const float*)d_in[8];
    const float* Wbil = (const float*)d_in[9];
    const float* bbil = (const float*)d_in[10];
    const float* Wr1  = (const float*)d_in[11];
    const float* br1  = (const float*)d_in[12];
    const float* Wr2  = (const float*)d_in[13];
    const float* br2  = (const float*)d_in[14];
    float* outp = (float*)d_out;

    // workspace (u16 elements): ~21 MB
    u16* obs_p   = (u16*)d_ws;                    // BN*256 packed
    u16* msgs_bf = obs_p   + (size_t)BN*256;      // BN*64 row-major
    u16* Wp1  = msgs_bf + (size_t)BN*64;          // 32768
    u16* Wp2  = Wp1  + 32768;
    u16* Wpc  = Wp2  + 8192;
    u16* Wpd  = Wpc  + 2048;
    u16* WpB  = Wpd  + 2048;
    u16* Wpr1 = WpB  + 65536;
    u16* Wpr2 = Wpr1 + 81920;

    prep_w_k<<<1008, 256, 0, stream>>>(W1, W2, Wc, Wd, Wbil, Wr1, Wr2,
                                       Wp1, Wp2, Wpc, Wpd, WpB, Wpr1, Wpr2);
    sendpack_k<<<BN/32, 256, 0, stream>>>(obs, obs_p, Wp1, b1, Wp2, b2,
                                          Wpc, bc, Wpd, bd, msgs_bf);
    relrecv_k<<<BN/64, 512, 0, stream>>>(obs_p, WpB, bbil, msgs_bf,
                                         Wpr1, br1, Wpr2, br2, outp);
}

// Round 3
// 56.371 us; speedup vs baseline: 1.0364x; 1.0364x over previous
//
#include <hip/hip_runtime.h>
#include <cstddef>

// Problem constants
#define BB   128
#define NN   256
#define DIMD 256
#define MSG  64
#define CDIM 32
#define TOPK 8
#define H1D  128
#define H2D  256
#define BN   (BB*NN)   // 32768 rows

typedef unsigned short u16;
typedef u16   u16x4  __attribute__((ext_vector_type(4)));
typedef u16   u16x8  __attribute__((ext_vector_type(8)));
typedef short short8 __attribute__((ext_vector_type(8)));
typedef float f32x4  __attribute__((ext_vector_type(4)));

__device__ __forceinline__ u16 f2bf(float f) {
    return (u16)((__float_as_uint(f) + 0x8000u) >> 16);
}
__device__ __forceinline__ float bf2f(u16 u) {
    return __uint_as_float(((unsigned)u) << 16);
}
// bf16 bits -> order-preserving u16 key (monotone: a<b as float => key(a)<key(b))
__device__ __forceinline__ u16 bf2key(u16 b) {
    return (u16)(b ^ ((b & 0x8000u) ? 0xFFFFu : 0x8000u));
}
__device__ __forceinline__ u16 key2bf(u16 k) {
    return (u16)(k ^ ((k & 0x8000u) ? 0x8000u : 0xFFFFu));
}
#define MFMA16(a,b,c) __builtin_amdgcn_mfma_f32_16x16x32_bf16((a),(b),(c),0,0,0)

// Fragment-linear packing (global): elem (tile=row/16, ls=row%16, kk=k/32,
// q=(k%32)/8, j=k%8) at ((tile*KB+kk)*64 + q*16 + ls)*8 + j. A wave's
// fragment load is one coalesced 1KB transaction.

// ---------------------------------------------------------------------------
// prep: weights fp32 [in][out] -> packed bf16. 1008 blocks exactly.
// ---------------------------------------------------------------------------
__global__ __launch_bounds__(256) void prep_w_k(
    const float* __restrict__ W1, const float* __restrict__ W2,
    const float* __restrict__ Wc, const float* __restrict__ Wd,
    const float* __restrict__ Wb, const float* __restrict__ Wr1,
    const float* __restrict__ Wr2,
    u16* __restrict__ Wp1, u16* __restrict__ Wp2, u16* __restrict__ Wpc,
    u16* __restrict__ Wpd, u16* __restrict__ WpB, u16* __restrict__ Wpr1,
    u16* __restrict__ Wpr2)
{
    const int t = blockIdx.x * 256 + threadIdx.x;   // 258048 exactly
    const float* src; u16* dst; int I, os, loc;
    if      (t <  32768) { src = W1;  dst = Wp1;  I = 256; os = 7; loc = t; }
    else if (t <  40960) { src = W2;  dst = Wp2;  I = 128; os = 6; loc = t - 32768; }
    else if (t <  43008) { src = Wc;  dst = Wpc;  I = 64;  os = 5; loc = t - 40960; }
    else if (t <  45056) { src = Wd;  dst = Wpd;  I = 32;  os = 6; loc = t - 43008; }
    else if (t < 110592) { src = Wb;  dst = WpB;  I = 256; os = 8; loc = t - 45056; }
    else if (t < 192512) { src = Wr1; dst = Wpr1; I = 320; os = 8; loc = t - 110592; }
    else                 { src = Wr2; dst = Wpr2; I = 256; os = 8; loc = t - 192512; }
    const int i = loc >> os;
    const int o = loc & ((1 << os) - 1);
    const int nt = o >> 4, ls = o & 15;
    const int KB = I >> 5;
    const int kk = i >> 5, q = (i & 31) >> 3, j = i & 7;
    dst[((size_t)(nt*KB + kk)*64 + q*16 + ls)*8 + j] = f2bf(src[loc]);
}

// ---------------------------------------------------------------------------
// sendpack: 32 rows/block, 4 waves. Stages fp32 obs -> bf16 LDS, emits
// packed obs_p (coalesced), runs the 4-layer send MLP (L1 A from LDS,
// B prefetched), writes msgs. Replaces the old obs-prep pass entirely.
// ---------------------------------------------------------------------------
__global__ __launch_bounds__(256) __attribute__((amdgpu_waves_per_eu(4, 4)))
void sendpack_k(
    const float* __restrict__ obs, u16* __restrict__ obs_p,
    const u16* __restrict__ Wp1, const float* __restrict__ b1,
    const u16* __restrict__ Wp2, const float* __restrict__ b2,
    const u16* __restrict__ Wpc, const float* __restrict__ bc,
    const u16* __restrict__ Wpd, const float* __restrict__ bd,
    u16* __restrict__ msgs_bf)
{
    __shared__ __align__(16) u16 sO[32][264];
    __shared__ __align__(16) u16 sH[32][136];
    __shared__ __align__(16) u16 sF[32][72];
    __shared__ __align__(16) u16 sC[32][40];
    const int t = threadIdx.x;
    const int w = t >> 6, l = t & 63, q = l >> 4, ls = l & 15;
    const int row0 = blockIdx.x * 32;
    const int tile0 = blockIdx.x * 2;

    // stage obs fp32 -> bf16 LDS (coalesced reads, one row per wave-step)
    {
        const float4* src = (const float4*)(obs + (size_t)row0 * 256);
        #pragma unroll
        for (int i = 0; i < 8; ++i) {
            const int idx = t + 256*i;
            const int r = idx >> 6, c4 = idx & 63;
            const float4 v = src[idx];
            u16x4 o;
            o[0] = f2bf(v.x); o[1] = f2bf(v.y); o[2] = f2bf(v.z); o[3] = f2bf(v.w);
            *(u16x4*)&sO[r][c4*4] = o;
        }
    }
    __syncthreads();
    // emit packed obs_p: LDS b128 reads -> coalesced 1KB global stores
    {
        #pragma unroll
        for (int i = 0; i < 4; ++i) {
            const int u = t + 256*i;                 // 1024 u16x8 units
            const int tile = u >> 9, kk = (u >> 6) & 7, lane = u & 63;
            const u16x8 v = *(const u16x8*)&sO[tile*16 + (lane & 15)][kk*32 + (lane >> 4)*8];
            *(u16x8*)(obs_p + (size_t)(tile0 + tile)*4096 + (size_t)(kk*64 + lane)*8) = v;
        }
    }
    // L1: 256 -> 128, relu; wave owns n-tiles {2w,2w+1}; A from LDS, B prefetched
    {
        f32x4 acc[2][2];
        #pragma unroll
        for (int mi = 0; mi < 2; ++mi)
            #pragma unroll
            for (int nn = 0; nn < 2; ++nn) acc[mi][nn] = (f32x4){0,0,0,0};
        short8 cb[2];
        #pragma unroll
        for (int nn = 0; nn < 2; ++nn)
            cb[nn] = *(const short8*)(Wp1 + ((size_t)((w*2+nn)*8))*512 + l*8);
        #pragma unroll
        for (int kk = 0; kk < 8; ++kk) {
            short8 nb[2];
            if (kk < 7) {
                #pragma unroll
                for (int nn = 0; nn < 2; ++nn)
                    nb[nn] = *(const short8*)(Wp1 + ((size_t)((w*2+nn)*8 + kk+1))*512 + l*8);
            }
            short8 a[2];
            a[0] = *(const short8*)&sO[ls][kk*32 + q*8];
            a[1] = *(const short8*)&sO[16 + ls][kk*32 + q*8];
            #pragma unroll
            for (int mi = 0; mi < 2; ++mi)
                #pragma unroll
                for (int nn = 0; nn < 2; ++nn)
                    acc[mi][nn] = MFMA16(a[mi], cb[nn], acc[mi][nn]);
            if (kk < 7) {
                #pragma unroll
                for (int nn = 0; nn < 2; ++nn) cb[nn] = nb[nn];
            }
        }
        #pragma unroll
        for (int nn = 0; nn < 2; ++nn) {
            const float bv = b1[(w*2+nn)*16 + ls];
            #pragma unroll
            for (int mi = 0; mi < 2; ++mi)
                #pragma unroll
                for (int r = 0; r < 4; ++r)
                    sH[mi*16 + q*4 + r][(w*2+nn)*16 + ls] = f2bf(fmaxf(acc[mi][nn][r] + bv, 0.0f));
        }
    }
    __syncthreads();
    // L2: 128 -> 64; wave owns n-tile w
    {
        f32x4 acc[2];
        acc[0] = (f32x4){0,0,0,0}; acc[1] = (f32x4){0,0,0,0};
        #pragma unroll
        for (int kk = 0; kk < 4; ++kk) {
            const int k0 = kk * 32;
            short8 a[2];
            a[0] = *(const short8*)(&sH[ls][k0 + q*8]);
            a[1] = *(const short8*)(&sH[16 + ls][k0 + q*8]);
            const short8 bf = *(const short8*)(Wp2 + ((size_t)(w*4 + kk)*64 + l)*8);
            acc[0] = MFMA16(a[0], bf, acc[0]);
            acc[1] = MFMA16(a[1], bf, acc[1]);
        }
        const float bv = b2[w*16 + ls];
        #pragma unroll
        for (int mi = 0; mi < 2; ++mi)
            #pragma unroll
            for (int r = 0; r < 4; ++r)
                sF[mi*16 + q*4 + r][w*16 + ls] = f2bf(acc[mi][r] + bv);
    }
    __syncthreads();
    // L3: 64 -> 32; waves 0,1 active
    if (w < 2) {
        f32x4 acc[2];
        acc[0] = (f32x4){0,0,0,0}; acc[1] = (f32x4){0,0,0,0};
        #pragma unroll
        for (int kk = 0; kk < 2; ++kk) {
            const int k0 = kk * 32;
            short8 a[2];
            a[0] = *(const short8*)(&sF[ls][k0 + q*8]);
            a[1] = *(const short8*)(&sF[16 + ls][k0 + q*8]);
            const short8 bf = *(const short8*)(Wpc + ((size_t)(w*2 + kk)*64 + l)*8);
            acc[0] = MFMA16(a[0], bf, acc[0]);
            acc[1] = MFMA16(a[1], bf, acc[1]);
        }
        const float bv = bc[w*16 + ls];
        #pragma unroll
        for (int mi = 0; mi < 2; ++mi)
            #pragma unroll
            for (int r = 0; r < 4; ++r)
                sC[mi*16 + q*4 + r][w*16 + ls] = f2bf(acc[mi][r] + bv);
    }
    __syncthreads();
    // L4: 32 -> 64; wave owns n-tile w; write msgs (row-major)
    {
        f32x4 acc[2];
        acc[0] = (f32x4){0,0,0,0}; acc[1] = (f32x4){0,0,0,0};
        short8 a[2];
        a[0] = *(const short8*)(&sC[ls][q*8]);
        a[1] = *(const short8*)(&sC[16 + ls][q*8]);
        const short8 bf = *(const short8*)(Wpd + ((size_t)w*64 + l)*8);
        acc[0] = MFMA16(a[0], bf, acc[0]);
        acc[1] = MFMA16(a[1], bf, acc[1]);
        const float bv = bd[w*16 + ls];
        #pragma unroll
        for (int mi = 0; mi < 2; ++mi)
            #pragma unroll
            for (int r = 0; r < 4; ++r)
                msgs_bf[(size_t)(row0 + mi*16 + q*4 + r)*MSG + w*16 + ls] = f2bf(acc[mi][r] + bv);
    }
}

// ---------------------------------------------------------------------------
// relrecv (fused): 64 rows of one batch per block, 512 threads / 8 waves.
//  R2 changes: (a) top-8 scan on packed u32 keys (sortable-int bf16 key<<8 |
//  (255-idx)) — one unsigned compare gives value order AND lowest-index
//  tie-break; insertion ladder and 8-lane merge are ~2x fewer VALU ops.
//  P3 epilogue stores keys directly into sS (scores only feed the scan).
//  (b) B-fragment prefetch deepened to 3 (pb[4][2]).
// ---------------------------------------------------------------------------
__global__ __launch_bounds__(512) __attribute__((amdgpu_waves_per_eu(4, 4)))
void relrecv_k(
    const u16* __restrict__ obs_p, const u16* __restrict__ WpB,
    const float* __restrict__ bbil, const u16* __restrict__ msgs_bf,
    const u16* __restrict__ Wpr1, const float* __restrict__ br1,
    const u16* __restrict__ Wpr2, const float* __restrict__ br2,
    float* __restrict__ out)
{
    __shared__ __align__(16) u16 sS[64][264];   // tmp -> score keys -> recvL1 out
    __shared__ __align__(16) u16 sA[64][72];    // agg, row-major [row][k]
    __shared__ __align__(16) u16 sObs[16384];   // block's 4 packed obs tiles
    __shared__ float sG[64][8];
    __shared__ unsigned short sI[64][8];
    const int t = threadIdx.x;
    const int w = t >> 6, l = t & 63, q = l >> 4, ls = l & 15;
    const int bid = blockIdx.x;        // 512
    const int xcd = bid & 7, idx = bid >> 3;   // idx in [0,64)
    const int b   = xcd * 16 + (idx >> 2);     // batch
    const int mc  = idx & 3;                   // 64-row chunk
    const int row0g = b * NN + mc * 64;
    const int mt0   = b * 16 + mc * 4;         // first of 4 m-tiles

    short8 pb[4][2];   // B-fragment pipeline buffers, depth-3 (reused per phase)

    // stage block's own obs tiles -> LDS (32KB contiguous, coalesced)
    {
        const u16x8* src = (const u16x8*)(obs_p + (size_t)mt0 * 4096);
        #pragma unroll
        for (int i = 0; i < 4; ++i)
            *(u16x8*)&sObs[(t + 512*i) * 8] = src[t + 512*i];
    }
    // P2 B preload (depth 3) — issued before the barrier; drains during wait
    #pragma unroll
    for (int d = 0; d < 3; ++d)
        #pragma unroll
        for (int nn = 0; nn < 2; ++nn)
            pb[d][nn] = *(const short8*)(WpB + ((size_t)((w*2+nn)*8 + d))*512 + l*8);
    __syncthreads();

    // P2: tmp[m][e]; wave owns e-tiles {2w,2w+1}; A from sObs, B 4-buffered
    {
        f32x4 acc[4][2];
        #pragma unroll
        for (int mi = 0; mi < 4; ++mi)
            #pragma unroll
            for (int nn = 0; nn < 2; ++nn) acc[mi][nn] = (f32x4){0,0,0,0};
        #pragma unroll
        for (int kk = 0; kk < 8; ++kk) {
            if (kk < 5) {
                #pragma unroll
                for (int nn = 0; nn < 2; ++nn)
                    pb[(kk+3)&3][nn] = *(const short8*)(WpB + ((size_t)((w*2+nn)*8 + kk+3))*512 + l*8);
            }
            short8 a[4];
            #pragma unroll
            for (int mi = 0; mi < 4; ++mi)
                a[mi] = *(const short8*)&sObs[mi*4096 + kk*512 + l*8];
            #pragma unroll
            for (int mi = 0; mi < 4; ++mi)
                #pragma unroll
                for (int nn = 0; nn < 2; ++nn)
                    acc[mi][nn] = MFMA16(a[mi], pb[kk&3][nn], acc[mi][nn]);
        }
        #pragma unroll
        for (int mi = 0; mi < 4; ++mi)
            #pragma unroll
            for (int nn = 0; nn < 2; ++nn)
                #pragma unroll
                for (int r = 0; r < 4; ++r)
                    sS[mi*16 + q*4 + r][(w*2+nn)*16 + ls] = f2bf(acc[mi][nn][r]);
    }
    // P3 B preload (obs_p batch rows) before the barrier
    #pragma unroll
    for (int d = 0; d < 3; ++d)
        #pragma unroll
        for (int nn = 0; nn < 2; ++nn)
            pb[d][nn] = *(const short8*)(obs_p + ((size_t)((b*16 + w*2+nn)*8 + d))*512 + l*8);
    __syncthreads();

    // P3: scores[m][j]; A (tmp) from LDS, B = packed obs_b rows, 4-buffered
    {
        const float bb = bbil[0];
        f32x4 acc[4][2];
        #pragma unroll
        for (int mi = 0; mi < 4; ++mi)
            #pragma unroll
            for (int nn = 0; nn < 2; ++nn) acc[mi][nn] = (f32x4){0,0,0,0};
        #pragma unroll
        for (int kk = 0; kk < 8; ++kk) {
            if (kk < 5) {
                #pragma unroll
                for (int nn = 0; nn < 2; ++nn)
                    pb[(kk+3)&3][nn] = *(const short8*)(obs_p + ((size_t)((b*16 + w*2+nn)*8 + kk+3))*512 + l*8);
            }
            const int k0 = kk * 32;
            short8 a[4];
            #pragma unroll
            for (int mi = 0; mi < 4; ++mi)
                a[mi] = *(const short8*)(&sS[mi*16 + ls][k0 + q*8]);
            #pragma unroll
            for (int mi = 0; mi < 4; ++mi)
                #pragma unroll
                for (int nn = 0; nn < 2; ++nn)
                    acc[mi][nn] = MFMA16(a[mi], pb[kk&3][nn], acc[mi][nn]);
        }
        __syncthreads();   // all tmp reads complete before overwrite
        // store order-preserving u16 keys (scan is the only consumer)
        #pragma unroll
        for (int mi = 0; mi < 4; ++mi)
            #pragma unroll
            for (int nn = 0; nn < 2; ++nn)
                #pragma unroll
                for (int r = 0; r < 4; ++r)
                    sS[mi*16 + q*4 + r][(w*2+nn)*16 + ls] = bf2key(f2bf(acc[mi][nn][r] + bb));
    }
    __syncthreads();
    // scan: 8 threads/row; packed u32 = (key<<8)|(255-idx): one unsigned
    // compare does value ordering AND lowest-index tie-break; keys unique.
    {
        const int r = t >> 3, g = t & 7;
        u16 buf[32];
        #pragma unroll
        for (int c = 0; c < 4; ++c)
            *(u16x8*)&buf[c*8] = *(const u16x8*)&sS[r][g*32 + c*8];
        unsigned val[8];
        #pragma unroll
        for (int j = 0; j < 8; ++j) val[j] = 0u;   // below any real candidate
        #pragma unroll
        for (int i = 0; i < 32; ++i) {
            const unsigned p = ((unsigned)buf[i] << 8) | (unsigned)(255 - (g*32 + i));
            if (p > val[7]) {
                #pragma unroll
                for (int j = 7; j >= 1; --j) {
                    const bool cj  = p > val[j];
                    const bool cjm = p > val[j-1];
                    val[j] = cj ? (cjm ? val[j-1] : p) : val[j];
                }
                val[0] = p > val[0] ? p : val[0];
            }
        }
        unsigned wv[8];
        #pragma unroll
        for (int k = 0; k < 8; ++k) {
            unsigned h = val[0], o;
            o = (unsigned)__shfl_xor((int)h, 1); h = o > h ? o : h;
            o = (unsigned)__shfl_xor((int)h, 2); h = o > h ? o : h;
            o = (unsigned)__shfl_xor((int)h, 4); h = o > h ? o : h;
            wv[k] = h;
            const bool won = (val[0] == h);   // unique winner: packed unique
            #pragma unroll
            for (int j = 0; j < 7; ++j) val[j] = won ? val[j+1] : val[j];
            val[7] = won ? 0u : val[7];
        }
        if (g == 0) {
            float v[8];
            #pragma unroll
            for (int k = 0; k < 8; ++k)
                v[k] = bf2f(key2bf((u16)(wv[k] >> 8)));
            float e[8]; float s = 0.0f;
            #pragma unroll
            for (int k = 0; k < 8; ++k) { e[k] = __expf(v[k] - v[0]); s += e[k]; }
            const float inv = 1.0f / s;
            #pragma unroll
            for (int k = 0; k < 8; ++k) {
                sG[r][k] = e[k] * inv;
                sI[r][k] = (unsigned short)(255 - (wv[k] & 255u));
            }
        }
    }
    // L1 B preload (depth 3) issued here — covered by the whole gather phase
    #pragma unroll
    for (int d = 0; d < 3; ++d)
        #pragma unroll
        for (int nn = 0; nn < 2; ++nn)
            pb[d][nn] = *(const short8*)(Wpr1 + ((size_t)((w*2+nn)*10 + d))*512 + l*8);
    // no barrier: sG/sI/gather rows are wave-private (wave w owns rows w*8..+7)
    // gather-aggregate: lane = msg column; fully unrolled so 64 loads pipeline
    {
        const u16* mb = msgs_bf + (size_t)b*NN*MSG + l;
        #pragma unroll
        for (int rr = 0; rr < 8; ++rr) {
            const int row = w*8 + rr;
            u16 mv[8];
            #pragma unroll
            for (int k = 0; k < 8; ++k)
                mv[k] = mb[(size_t)sI[row][k]*MSG];
            float a = 0.0f;
            #pragma unroll
            for (int k = 0; k < 8; ++k)
                a = fmaf(sG[row][k], bf2f(mv[k]), a);
            sA[row][l] = f2bf(a);
        }
    }
    __syncthreads();
    // recv L1: K=320 -> 256, relu; A: obs (sObs LDS, kk<8) + agg (sA, kk 8,9)
    {
        f32x4 acc[4][2];
        #pragma unroll
        for (int mi = 0; mi < 4; ++mi)
            #pragma unroll
            for (int nn = 0; nn < 2; ++nn) acc[mi][nn] = (f32x4){0,0,0,0};
        #pragma unroll
        for (int kk = 0; kk < 10; ++kk) {
            if (kk < 7) {
                #pragma unroll
                for (int nn = 0; nn < 2; ++nn)
                    pb[(kk+3)&3][nn] = *(const short8*)(Wpr1 + ((size_t)((w*2+nn)*10 + kk+3))*512 + l*8);
            }
            short8 a[4];
            if (kk < 8) {
                #pragma unroll
                for (int mi = 0; mi < 4; ++mi)
                    a[mi] = *(const short8*)&sObs[mi*4096 + kk*512 + l*8];
            } else {
                #pragma unroll
                for (int mi = 0; mi < 4; ++mi)
                    a[mi] = *(const short8*)&sA[mi*16 + ls][(kk-8)*32 + q*8];
            }
            #pragma unroll
            for (int mi = 0; mi < 4; ++mi)
                #pragma unroll
                for (int nn = 0; nn < 2; ++nn)
                    acc[mi][nn] = MFMA16(a[mi], pb[kk&3][nn], acc[mi][nn]);
        }
        // L2 B preload (depth 3) before the barrier (drains during epilogue)
        #pragma unroll
        for (int d = 0; d < 3; ++d)
            #pragma unroll
            for (int nn = 0; nn < 2; ++nn)
                pb[d][nn] = *(const short8*)(Wpr2 + ((size_t)((w*2+nn)*8 + d))*512 + l*8);
        __syncthreads();   // sS keys fully consumed (scan done) before reuse
        #pragma unroll
        for (int nn = 0; nn < 2; ++nn) {
            const float bv = br1[(w*2+nn)*16 + ls];
            #pragma unroll
            for (int mi = 0; mi < 4; ++mi)
                #pragma unroll
                for (int r = 0; r < 4; ++r)
                    sS[mi*16 + q*4 + r][(w*2+nn)*16 + ls] = f2bf(fmaxf(acc[mi][nn][r] + bv, 0.0f));
        }
    }
    __syncthreads();
    // recv L2: 256 -> 256, fp32 out; A from LDS, B Wpr2 4-buffered
    {
        f32x4 acc[4][2];
        #pragma unroll
        for (int mi = 0; mi < 4; ++mi)
            #pragma unroll
            for (int nn = 0; nn < 2; ++nn) acc[mi][nn] = (f32x4){0,0,0,0};
        #pragma unroll
        for (int kk = 0; kk < 8; ++kk) {
            if (kk < 5) {
                #pragma unroll
                for (int nn = 0; nn < 2; ++nn)
                    pb[(kk+3)&3][nn] = *(const short8*)(Wpr2 + ((size_t)((w*2+nn)*8 + kk+3))*512 + l*8);
            }
            const int k0 = kk * 32;
            short8 a[4];
            #pragma unroll
            for (int mi = 0; mi < 4; ++mi)
                a[mi] = *(const short8*)(&sS[mi*16 + ls][k0 + q*8]);
            #pragma unroll
            for (int mi = 0; mi < 4; ++mi)
                #pragma unroll
                for (int nn = 0; nn < 2; ++nn)
                    acc[mi][nn] = MFMA16(a[mi], pb[kk&3][nn], acc[mi][nn]);
        }
        #pragma unroll
        for (int nn = 0; nn < 2; ++nn) {
            const float bv = br2[(w*2+nn)*16 + ls];
            #pragma unroll
            for (int mi = 0; mi < 4; ++mi)
                #pragma unroll
                for (int r = 0; r < 4; ++r)
                    out[(size_t)(row0g + mi*16 + q*4 + r)*DIMD + (w*2+nn)*16 + ls] = acc[mi][nn][r] + bv;
        }
    }
}

// ---------------------------------------------------------------------------
extern "C" void kernel_launch(void* const* d_in, const int* in_sizes, int n_in,
                              void* d_out, int out_size, void* d_ws, size_t ws_size,
                              hipStream_t stream)
{
    (void)in_sizes; (void)n_in; (void)out_size; (void)ws_size;
    const float* obs  = (const float*)d_in[0];
    const float* W1   = (const float*)d_in[1];
    const float* b1   = (const float*)d_in[2];
    const float* W2   = (const float*)d_in[3];
    const float* b2   = (const float*)d_in[4];
    const float* Wc   = (const float*)d_in[5];
    const float* bc   = (const float*)d_in[6];
    const float* Wd   = (const float*)d_in[7];
    const float* bd   = (const float*)d_in[8];
    const float* Wbil = (const float*)d_in[9];
    const float* bbil = (const float*)d_in[10];
    const float* Wr1  = (const float*)d_in[11];
    const float* br1  = (const float*)d_in[12];
    const float* Wr2  = (const float*)d_in[13];
    const float* br2  = (const float*)d_in[14];
    float* outp = (float*)d_out;

    // workspace (u16 elements): ~21 MB
    u16* obs_p   = (u16*)d_ws;                    // BN*256 packed
    u16* msgs_bf = obs_p   + (size_t)BN*256;      // BN*64 row-major
    u16* Wp1  = msgs_bf + (size_t)BN*64;          // 32768
    u16* Wp2  = Wp1  + 32768;
    u16* Wpc  = Wp2  + 8192;
    u16* Wpd  = Wpc  + 2048;
    u16* WpB  = Wpd  + 2048;
    u16* Wpr1 = WpB  + 65536;
    u16* Wpr2 = Wpr1 + 81920;

    prep_w_k<<<1008, 256, 0, stream>>>(W1, W2, Wc, Wd, Wbil, Wr1, Wr2,
                                       Wp1, Wp2, Wpc, Wpd, WpB, Wpr1, Wpr2);
    sendpack_k<<<BN/32, 256, 0, stream>>>(obs, obs_p, Wp1, b1, Wp2, b2,
                                          Wpc, bc, Wpd, bd, msgs_bf);
    relrecv_k<<<BN/64, 512, 0, stream>>>(obs_p, WpB, bbil, msgs_bf,
                                         Wpr1, br1, Wpr2, br2, outp);
}